// Round 4
// baseline (1283.610 us; speedup 1.0000x reference)
//
#include <hip/hip_runtime.h>
#include <math.h>

// FineGrainLoss: B=96, n1=196 (image tokens), n2=77 (text tokens), d=512.
#define BB 96
#define N1 196
#define N2 77
#define DD 512

#define MT 13   // M tiles of 16 (208 rows, 196 valid)
#define NT 5    // N tiles of 16 (80 cols, 77 valid)

#define IMGN (BB * N1 * DD)
#define TXTN (BB * N2 * DD)

typedef short s8v __attribute__((ext_vector_type(8)));   // 8 bf16 (4 VGPR)
typedef float f4v __attribute__((ext_vector_type(4)));   // MFMA C/D

__device__ __forceinline__ unsigned short f2bf_rn(float x) {
    unsigned int u = __float_as_uint(x);
    unsigned int r = (u + 0x7fffu + ((u >> 16) & 1u)) >> 16;
    return (unsigned short)r;
}
__device__ __forceinline__ float bf2f(unsigned short h) {
    return __uint_as_float(((unsigned int)h) << 16);
}

// fp32 -> (hi, lo) bf16 split, precompute pass.
__global__ void convert_kernel(const float* __restrict__ src,
                               unsigned short* __restrict__ hi,
                               unsigned short* __restrict__ lo, int n) {
    int i = (blockIdx.x * blockDim.x + threadIdx.x) * 4;
    if (i >= n) return;
    float4 v = *(const float4*)(src + i);
    ushort4 h, l;
    h.x = f2bf_rn(v.x); l.x = f2bf_rn(v.x - bf2f(h.x));
    h.y = f2bf_rn(v.y); l.y = f2bf_rn(v.y - bf2f(h.y));
    h.z = f2bf_rn(v.z); l.z = f2bf_rn(v.z - bf2f(h.z));
    h.w = f2bf_rn(v.w); l.w = f2bf_rn(v.w - bf2f(h.w));
    *(ushort4*)(hi + i) = h;
    *(ushort4*)(lo + i) = l;
}

// Fetch one (hi, lo) fragment pair at element offset `off`.
// PRE: 16B vector loads from pre-split arrays. !PRE: fp32 load + split.
template <bool PRE>
__device__ __forceinline__ void fetch2(const unsigned short* __restrict__ hB,
                                       const unsigned short* __restrict__ lB,
                                       const float* __restrict__ fB, int off,
                                       s8v& h, s8v& l) {
    if constexpr (PRE) {
        h = *(const s8v*)(hB + off);
        l = *(const s8v*)(lB + off);
    } else {
        float4 v0 = *(const float4*)(fB + off);
        float4 v1 = *(const float4*)(fB + off + 4);
        float x[8] = {v0.x, v0.y, v0.z, v0.w, v1.x, v1.y, v1.z, v1.w};
#pragma unroll
        for (int e = 0; e < 8; ++e) {
            unsigned short hh = f2bf_rn(x[e]);
            h[e] = (short)hh;
            l[e] = (short)f2bf_rn(x[e] - bf2f(hh));
        }
    }
}

// One K=32 step for this wave's unit range [U0,U1). Units strip-major
// u = strip*NT + ct. A-frags loaded with distance-1 strip prefetch.
template <bool PRE, int U0, int U1>
__device__ __forceinline__ void compute_step(
    const unsigned short* __restrict__ aHi, const unsigned short* __restrict__ aLo,
    const float* __restrict__ aF, const int* __restrict__ offA, int k0,
    const s8v* __restrict__ bh, const s8v* __restrict__ bl, f4v* __restrict__ acc)
{
    constexpr int S0 = U0 / NT, S1 = (U1 - 1) / NT, NS = S1 - S0 + 1;
    s8v ah, al, ah2, al2;
    fetch2<PRE>(aHi, aLo, aF, offA[0] + k0, ah, al);
#pragma unroll
    for (int i = 0; i < NS; ++i) {
        if (i + 1 < NS) fetch2<PRE>(aHi, aLo, aF, offA[i + 1] + k0, ah2, al2);
        const int s = S0 + i;
#pragma unroll
        for (int ct = 0; ct < NT; ++ct) {
            const int u = s * NT + ct;
            if (u >= U0 && u < U1) {
                f4v c = acc[u - U0];
                c = __builtin_amdgcn_mfma_f32_16x16x32_bf16(ah, bh[ct], c, 0, 0, 0);
                c = __builtin_amdgcn_mfma_f32_16x16x32_bf16(ah, bl[ct], c, 0, 0, 0);
                c = __builtin_amdgcn_mfma_f32_16x16x32_bf16(al, bh[ct], c, 0, 0, 0);
                acc[u - U0] = c;
            }
        }
        ah = ah2; al = al2;
    }
}

// Full K loop for one wave: B-frags ping-pong double-buffered in registers
// (prefetch distance = one full step), no LDS, no barriers.
template <bool PRE, int U0, int U1>
__device__ __forceinline__ void run_wave(
    const float* __restrict__ imgF, const float* __restrict__ txtF,
    const unsigned short* __restrict__ imgHi, const unsigned short* __restrict__ imgLo,
    const unsigned short* __restrict__ txtHi, const unsigned short* __restrict__ txtLo,
    int bi, int bt, int lm, int lq, f4v* __restrict__ acc)
{
    constexpr int S0 = U0 / NT, S1 = (U1 - 1) / NT, NS = S1 - S0 + 1;
    int offA[NS], offB[NT];
#pragma unroll
    for (int i = 0; i < NS; ++i) {
        int q = (S0 + i) * 16 + lm; q = q > (N1 - 1) ? (N1 - 1) : q;
        offA[i] = (bi * N1 + q) * DD + lq * 8;
    }
#pragma unroll
    for (int ct = 0; ct < NT; ++ct) {
        int r = ct * 16 + lm; r = r > (N2 - 1) ? (N2 - 1) : r;
        offB[ct] = (bt * N2 + r) * DD + lq * 8;
    }

    s8v bh0[NT], bl0[NT], bh1[NT], bl1[NT];
#pragma unroll
    for (int ct = 0; ct < NT; ++ct)
        fetch2<PRE>(txtHi, txtLo, txtF, offB[ct], bh0[ct], bl0[ct]);

#pragma unroll 1
    for (int kc = 0; kc < 16; kc += 2) {
#pragma unroll
        for (int ct = 0; ct < NT; ++ct)
            fetch2<PRE>(txtHi, txtLo, txtF, offB[ct] + (kc + 1) * 32, bh1[ct], bl1[ct]);
        compute_step<PRE, U0, U1>(imgHi, imgLo, imgF, offA, kc * 32, bh0, bl0, acc);
        if (kc + 2 < 16) {
#pragma unroll
            for (int ct = 0; ct < NT; ++ct)
                fetch2<PRE>(txtHi, txtLo, txtF, offB[ct] + (kc + 2) * 32, bh0[ct], bl0[ct]);
        }
        compute_step<PRE, U0, U1>(imgHi, imgLo, imgF, offA, (kc + 1) * 32, bh1, bl1, acc);
    }
}

// Per-wave reduction partials. C/D layout: col = lane&15, row = (lane>>4)*4+reg.
// rp: [13 strips][4 waves][16 rows], cp: [80 cols][4 waves].
template <int U0, int U1>
__device__ __forceinline__ void reduce_phase1(const f4v* __restrict__ acc, int wave,
                                              int lq, int lm,
                                              float* __restrict__ rp,
                                              float* __restrict__ cp) {
    constexpr int S0 = U0 / NT;
    constexpr int S1 = (U1 - 1) / NT;
    constexpr int NS = S1 - S0 + 1;
    float colm[NT];
#pragma unroll
    for (int ct = 0; ct < NT; ++ct) colm[ct] = -INFINITY;
    float rowm[NS][4];
#pragma unroll
    for (int i = 0; i < NS; ++i)
#pragma unroll
        for (int r = 0; r < 4; ++r) rowm[i][r] = -INFINITY;

#pragma unroll
    for (int u = U0; u < U1; ++u) {
        const int s = u / NT, ct = u % NT;
        f4v a = acc[u - U0];
        // column partials: mask rows >=196 (strip 12, lq>0)
        bool rows_ok = (s != MT - 1) || (lq == 0);
        float cm = fmaxf(fmaxf(a[0], a[1]), fmaxf(a[2], a[3]));
        colm[ct] = fmaxf(colm[ct], rows_ok ? cm : -INFINITY);
        // row partials: mask cols >=77 (ct 4, lm>=13)
        bool col_ok = (ct != NT - 1) || (lm < N2 - 64);
#pragma unroll
        for (int r = 0; r < 4; ++r)
            rowm[s - S0][r] = fmaxf(rowm[s - S0][r], col_ok ? a[r] : -INFINITY);
    }
#pragma unroll
    for (int ct = 0; ct < NT; ++ct) {
        float m = colm[ct];
        m = fmaxf(m, __shfl_xor(m, 16));
        m = fmaxf(m, __shfl_xor(m, 32));
        if (lq == 0) cp[(ct * 16 + lm) * 4 + wave] = m;
    }
#pragma unroll
    for (int i = 0; i < NS; ++i) {
#pragma unroll
        for (int r = 0; r < 4; ++r) {
            float m = rowm[i][r];
            m = fmaxf(m, __shfl_xor(m, 1));
            m = fmaxf(m, __shfl_xor(m, 2));
            m = fmaxf(m, __shfl_xor(m, 4));
            m = fmaxf(m, __shfl_xor(m, 8));
            if (lm == 0) rp[(S0 + i) * 64 + wave * 16 + lq * 4 + r] = m;
        }
    }
}

// One block per (bi, bt): S[208x80] = img[bi].txt[bt]^T, triple-MFMA bf16
// split, all operands direct global->VGPR (L1/L2 do the sharing; no LDS
// staging, no barriers in the K loop). LDS only for the tiny epilogue.
template <bool PRE>
__global__ __launch_bounds__(256, 2) void sim_mfma_kernel(
    const float* __restrict__ imgF, const float* __restrict__ txtF,
    const unsigned short* __restrict__ imgHi, const unsigned short* __restrict__ imgLo,
    const unsigned short* __restrict__ txtHi, const unsigned short* __restrict__ txtLo,
    float* __restrict__ i2t, float* __restrict__ t2i)
{
    const int bt = blockIdx.x, bi = blockIdx.y;
    const int tid = threadIdx.x;
    const int wave = tid >> 6, lane = tid & 63;
    const int lm = lane & 15;
    const int lq = lane >> 4;

    __shared__ float rp[MT * 64];   // 832: [strip][wave][16 rows]
    __shared__ float cp[80 * 4];    // 320: [col][wave]
    __shared__ float sws[8];

    f4v acc[17];
#pragma unroll
    for (int i = 0; i < 17; ++i) acc[i] = (f4v){0.f, 0.f, 0.f, 0.f};

    // Unit split {16,16,16,17}; every wave spans exactly 4 strips.
    if (wave == 0)      run_wave<PRE, 0, 16>(imgF, txtF, imgHi, imgLo, txtHi, txtLo, bi, bt, lm, lq, acc);
    else if (wave == 1) run_wave<PRE, 16, 32>(imgF, txtF, imgHi, imgLo, txtHi, txtLo, bi, bt, lm, lq, acc);
    else if (wave == 2) run_wave<PRE, 32, 48>(imgF, txtF, imgHi, imgLo, txtHi, txtLo, bi, bt, lm, lq, acc);
    else                run_wave<PRE, 48, 65>(imgF, txtF, imgHi, imgLo, txtHi, txtLo, bi, bt, lm, lq, acc);

    // ---- fused reductions ----
    for (int i = tid; i < MT * 64; i += 256) rp[i] = -INFINITY;
    __syncthreads();
    if (wave == 0)      reduce_phase1<0, 16>(acc, wave, lq, lm, rp, cp);
    else if (wave == 1) reduce_phase1<16, 32>(acc, wave, lq, lm, rp, cp);
    else if (wave == 2) reduce_phase1<32, 48>(acc, wave, lq, lm, rp, cp);
    else                reduce_phase1<48, 65>(acc, wave, lq, lm, rp, cp);
    __syncthreads();

    float v = 0.f;
    if (tid < N1) {
        int s = tid >> 4, r = tid & 15;
        float m = rp[s * 64 + r];
        m = fmaxf(m, rp[s * 64 + 16 + r]);
        m = fmaxf(m, rp[s * 64 + 32 + r]);
        m = fmaxf(m, rp[s * 64 + 48 + r]);
        v = m;
    }
    v += __shfl_xor(v, 1);  v += __shfl_xor(v, 2);  v += __shfl_xor(v, 4);
    v += __shfl_xor(v, 8);  v += __shfl_xor(v, 16); v += __shfl_xor(v, 32);
    float cv = 0.f;
    if (tid < N2) {
        cv = fmaxf(fmaxf(cp[tid * 4 + 0], cp[tid * 4 + 1]),
                   fmaxf(cp[tid * 4 + 2], cp[tid * 4 + 3]));
    }
    cv += __shfl_xor(cv, 1);  cv += __shfl_xor(cv, 2);  cv += __shfl_xor(cv, 4);
    cv += __shfl_xor(cv, 8);  cv += __shfl_xor(cv, 16); cv += __shfl_xor(cv, 32);
    if (lane == 0) { sws[wave] = v; sws[4 + wave] = cv; }
    __syncthreads();
    if (tid == 0)
        i2t[bi * BB + bt] = (sws[0] + sws[1] + sws[2] + sws[3]) * (1.f / (float)N1);
    if (tid == 1)
        t2i[bt * BB + bi] = (sws[4] + sws[5] + sws[6] + sws[7]) * (1.f / (float)N2);
}

// CE with arange labels over both [B,B] logit matrices.
__global__ __launch_bounds__(256) void ce_kernel(
    const float* __restrict__ i2t, const float* __restrict__ t2i,
    float* __restrict__ out)
{
    const int tid = threadIdx.x;
    const int wid = tid >> 6;
    const int lane = tid & 63;

    float contrib = 0.f;
    if (tid < 2 * BB) {
        const float* M = (tid < BB) ? i2t : t2i;
        const int b = (tid < BB) ? tid : tid - BB;
        const float* row = M + b * BB;
        float mx = row[0];
#pragma unroll 1
        for (int c = 1; c < BB; ++c) mx = fmaxf(mx, row[c]);
        float s = 0.f;
#pragma unroll 1
        for (int c = 0; c < BB; ++c) s += expf(row[c] - mx);
        float lse = mx + logf(s);
        contrib = row[b] - lse;
    }
    contrib += __shfl_xor(contrib, 1);
    contrib += __shfl_xor(contrib, 2);
    contrib += __shfl_xor(contrib, 4);
    contrib += __shfl_xor(contrib, 8);
    contrib += __shfl_xor(contrib, 16);
    contrib += __shfl_xor(contrib, 32);

    __shared__ float s_part[4];
    if (lane == 0) s_part[wid] = contrib;
    __syncthreads();
    if (tid == 0) {
        float total = s_part[0] + s_part[1] + s_part[2] + s_part[3];
        out[0] = -total * (1.f / (float)(2 * BB));
    }
}

extern "C" void kernel_launch(void* const* d_in, const int* in_sizes, int n_in,
                              void* d_out, int out_size, void* d_ws, size_t ws_size,
                              hipStream_t stream) {
    const float* img = (const float*)d_in[0];   // [96,196,512] fp32
    const float* txt = (const float*)d_in[1];   // [96,77,512] fp32
    float* i2t = (float*)d_ws;                  // [96,96]
    float* t2i = i2t + BB * BB;                 // [96,96]

    const size_t conv_off = 2 * BB * BB * sizeof(float);
    const size_t need = conv_off + (size_t)(IMGN + TXTN) * 2 * sizeof(unsigned short);

    dim3 grid(BB, BB);
    if (ws_size >= need) {
        unsigned short* imgHi = (unsigned short*)((char*)d_ws + conv_off);
        unsigned short* imgLo = imgHi + IMGN;
        unsigned short* txtHi = imgLo + IMGN;
        unsigned short* txtLo = txtHi + TXTN;
        convert_kernel<<<(IMGN / 4 + 255) / 256, 256, 0, stream>>>(img, imgHi, imgLo, IMGN);
        convert_kernel<<<(TXTN / 4 + 255) / 256, 256, 0, stream>>>(txt, txtHi, txtLo, TXTN);
        sim_mfma_kernel<true><<<grid, 256, 0, stream>>>(
            img, txt, imgHi, imgLo, txtHi, txtLo, i2t, t2i);
    } else {
        sim_mfma_kernel<false><<<grid, 256, 0, stream>>>(
            img, txt, nullptr, nullptr, nullptr, nullptr, i2t, t2i);
    }
    ce_kernel<<<1, 256, 0, stream>>>(i2t, t2i, (float*)d_out);
}